// Round 2
// baseline (7548.377 us; speedup 1.0000x reference)
//
#include <hip/hip_runtime.h>

typedef unsigned short u16;
typedef unsigned int   u32;
typedef _Float16       f16;
typedef __attribute__((ext_vector_type(4))) _Float16 v4h;
typedef __attribute__((ext_vector_type(8))) _Float16 v8h;   // MFMA A/B frag (4 VGPRs)
typedef __attribute__((ext_vector_type(4))) float    v4f;   // MFMA C/D frag

#define TT 2048
#define BB 8

static __device__ __forceinline__ float sigmoidf_(float x){
    return 1.0f / (1.0f + __expf(-x));
}
static __device__ __forceinline__ float allreduce64(float v){
    #pragma unroll
    for (int off = 32; off > 0; off >>= 1) v += __shfl_xor(v, off, 64);
    return v;
}

// ---------------- diagnostic: fills d_out with sentinel if ws too small ----------------
__global__ __launch_bounds__(256) void sentinel_fill(float* __restrict__ out, int n){
    int i = blockIdx.x * 256 + threadIdx.x;
    if (i < n) out[i] = 12345.0f;
}

// ---------------- LayerNorm: x (16384x1024 f32) -> xn (fp16) ----------------
__global__ __launch_bounds__(256) void ln_kernel(
    const float* __restrict__ x, const float* __restrict__ g,
    const float* __restrict__ bta, f16* __restrict__ xn)
{
    const int row = blockIdx.x;
    const int tid = threadIdx.x;
    const float4 v = ((const float4*)(x + (size_t)row * 1024))[tid];
    float s  = v.x + v.y + v.z + v.w;
    float s2 = v.x*v.x + v.y*v.y + v.z*v.z + v.w*v.w;
    #pragma unroll
    for (int off = 32; off > 0; off >>= 1){
        s  += __shfl_xor(s,  off, 64);
        s2 += __shfl_xor(s2, off, 64);
    }
    __shared__ float rs[4], rq[4];
    const int wv = tid >> 6, lane = tid & 63;
    if (lane == 0){ rs[wv] = s; rq[wv] = s2; }
    __syncthreads();
    s  = rs[0] + rs[1] + rs[2] + rs[3];
    s2 = rq[0] + rq[1] + rq[2] + rq[3];
    const float mu   = s * (1.0f / 1024.0f);
    const float var  = s2 * (1.0f / 1024.0f) - mu * mu;
    const float rstd = rsqrtf(var + 1e-5f);
    const float4 gv = ((const float4*)g)[tid];
    const float4 bv = ((const float4*)bta)[tid];
    v4h o;
    o.x = (f16)((v.x - mu) * rstd * gv.x + bv.x);
    o.y = (f16)((v.y - mu) * rstd * gv.y + bv.y);
    o.z = (f16)((v.z - mu) * rstd * gv.z + bv.z);
    o.w = (f16)((v.w - mu) * rstd * gv.w + bv.w);
    ((v4h*)(xn + (size_t)row * 1024))[tid] = o;
}

// ------- transpose+cast 5 weight mats (1024x1024 f32, [k][n]) -> fp16 [n][k] -------
__global__ __launch_bounds__(256) void transpose5(
    const float* __restrict__ Wq, const float* __restrict__ Wk,
    const float* __restrict__ Wv, const float* __restrict__ Wa,
    const float* __restrict__ Wo, f16* __restrict__ wcat, f16* __restrict__ wot)
{
    __shared__ float tile[32][33];
    const int z = blockIdx.z;
    const float* src = (z==0)?Wq:(z==1)?Wk:(z==2)?Wv:(z==3)?Wa:Wo;
    f16* dst = (z < 4) ? (wcat + (size_t)z * 1024 * 1024) : wot;
    const int bx = blockIdx.x * 32, by = blockIdx.y * 32;
    const int tx = threadIdx.x, ty = threadIdx.y;
    #pragma unroll
    for (int i = 0; i < 4; ++i)
        tile[ty + i*8][tx] = src[(size_t)(by + ty + i*8) * 1024 + bx + tx];
    __syncthreads();
    #pragma unroll
    for (int i = 0; i < 4; ++i)
        dst[(size_t)(bx + ty + i*8) * 1024 + by + tx] = (f16)tile[tx][ty + i*8];
}

// ---------------- fp16 MFMA GEMM, B transposed (N x K). BM=BN=128, BK=64 ----------------
// MODE 0: scatter fp16 outputs to Q/K/V/A segment buffers by col>>10; seg 3 gets sigmoid(v+ba)
// MODE 1: C = A@B + resid, f32 out
template<int MODE>
__global__ __launch_bounds__(256) void gemm_bt(
    const f16* __restrict__ A, const f16* __restrict__ Bt,
    int M, int N, int K,
    const float* __restrict__ ba, const float* __restrict__ resid,
    float* __restrict__ Cf,
    f16* __restrict__ Qb, f16* __restrict__ Kb,
    f16* __restrict__ Vb, f16* __restrict__ Ab)
{
    __shared__ f16 As[128 * 72];   // +8 pad per row (16 B): frag reads stay 16B-aligned
    __shared__ f16 Bs[128 * 72];
    const int tid = threadIdx.x;
    const int bm = blockIdx.x, bn = blockIdx.y;
    const int wv = tid >> 6, lane = tid & 63;
    const int l15 = lane & 15, quad = lane >> 4;
    const int mb = (wv >> 1) * 64, nb = (wv & 1) * 64;
    v4f acc[4][4];
    const v4f vzero = {0.0f, 0.0f, 0.0f, 0.0f};
    #pragma unroll
    for (int i = 0; i < 4; ++i)
        #pragma unroll
        for (int j = 0; j < 4; ++j) acc[i][j] = vzero;

    const f16* Ag = A  + (size_t)bm * 128 * K;
    const f16* Bg = Bt + (size_t)bn * 128 * K;

    for (int k0 = 0; k0 < K; k0 += 64){
        __syncthreads();
        #pragma unroll
        for (int it = 0; it < 4; ++it){
            const int ch = tid + it * 256;
            const int r = ch >> 3, c = ch & 7;          // 8 chunks of 8 halves per 64-wide row
            const uint4 da = *(const uint4*)(Ag + (size_t)r * K + k0 + c * 8);
            *(uint4*)(&As[r * 72 + c * 8]) = da;
            const uint4 db = *(const uint4*)(Bg + (size_t)r * K + k0 + c * 8);
            *(uint4*)(&Bs[r * 72 + c * 8]) = db;
        }
        __syncthreads();
        #pragma unroll
        for (int kk = 0; kk < 2; ++kk){
            v8h af[4], bfr[4];
            #pragma unroll
            for (int i = 0; i < 4; ++i){
                // A frag: m = l15, k = quad*8 + j ; B frag (from Bt rows): n = l15, same k
                af[i]  = *(const v8h*)(&As[(mb + i*16 + l15) * 72 + kk*32 + quad*8]);
                bfr[i] = *(const v8h*)(&Bs[(nb + i*16 + l15) * 72 + kk*32 + quad*8]);
            }
            #pragma unroll
            for (int i = 0; i < 4; ++i)
                #pragma unroll
                for (int j = 0; j < 4; ++j)
                    acc[i][j] = __builtin_amdgcn_mfma_f32_16x16x32_f16(af[i], bfr[j], acc[i][j], 0, 0, 0);
        }
    }
    // C/D layout: col = l15, row = quad*4 + r  [measured m89/m91]
    const int seg = (bn * 128) >> 10;   // wave-uniform: which of Q/K/V/A this block's cols hit
    f16* dst = (seg == 0) ? Qb : (seg == 1) ? Kb : (seg == 2) ? Vb : Ab;
    #pragma unroll
    for (int i = 0; i < 4; ++i){
        #pragma unroll
        for (int j = 0; j < 4; ++j){
            const int col = bn * 128 + nb + j * 16 + l15;
            const int c   = col & 1023;
            #pragma unroll
            for (int r = 0; r < 4; ++r){
                const int row = bm * 128 + mb + i * 16 + quad * 4 + r;
                float val = acc[i][j][r];
                if (MODE == 0){
                    if (seg == 3) val = sigmoidf_(val + ba[c]);
                    dst[(size_t)row * 1024 + c] = (f16)val;
                } else {
                    Cf[(size_t)row * N + col] = val + resid[(size_t)row * N + col];
                }
            }
        }
    }
}

// ---------------- beta: sigmoid(xn @ Wb + bb), stored chain-major [b*16+h][t] ----------------
__global__ __launch_bounds__(256) void beta_kernel(
    const f16* __restrict__ xn, const float* __restrict__ Wb,
    const float* __restrict__ bb, float* __restrict__ betaw)
{
    const int row = blockIdx.x;
    const int b = row >> 11, t = row & 2047;
    const int wv = threadIdx.x >> 6, lane = threadIdx.x & 63;
    const f16* xr = xn + (size_t)row * 1024;
    #pragma unroll
    for (int hh = 0; hh < 4; ++hh){
        const int h = wv * 4 + hh;
        float acc = 0.0f;
        #pragma unroll 4
        for (int k = lane; k < 1024; k += 64)
            acc += (float)xr[k] * Wb[k * 16 + h];
        acc = allreduce64(acc);
        if (lane == 0)
            betaw[((size_t)(b * 16 + h)) * 2048 + t] = sigmoidf_(acc + bb[h]);
    }
}

// ---------------- sequential scan: 1 wave per (b,h) chain ----------------
// lane i owns M row i (Mk=M*kn lane-local); lane e owns S column e (kproj, o lane-local).
// Cross-lane vectors (kn, a, q, ktld) broadcast via same-address LDS reads (conflict-free).
// No __syncthreads (single wave; avoids vmcnt(0) drain that would kill the t+1 prefetch).
__global__ __launch_bounds__(64, 1) void scan_kernel(
    const f16* __restrict__ Qb, const f16* __restrict__ Kb,
    const f16* __restrict__ Vb, const f16* __restrict__ Ab,
    const float* __restrict__ beta, const float* __restrict__ rgm,
    f16* __restrict__ O)
{
    const int chain = blockIdx.x;           // b*16 + h
    const int b = chain >> 4, h = chain & 15;
    const int lane = threadIdx.x;
    const float gm = sigmoidf_(rgm[h]);

    float m[64], s[64];
    #pragma unroll
    for (int j = 0; j < 64; ++j){
        m[j] = (lane == j) ? 1e-6f : 0.0f;  // M0 = EPS*I
        s[j] = 0.0f;
    }

    __shared__ float4 pack[64];             // {kn, a, q, ktld}
    const size_t base = ((size_t)(b * TT)) * 1024 + h * 64 + lane;
    const f16* pq = Qb + base;
    const f16* pk = Kb + base;
    const f16* pv = Vb + base;
    const f16* pa = Ab + base;
    const float* bp = beta + (size_t)chain * TT;
    f16* op = O + base;

    float qv = (float)pq[0], kv = (float)pk[0], vv = (float)pv[0], av = (float)pa[0];

    for (int t = 0; t < TT; ++t){
        // prefetch t+1 (dep distance ~1 full iter covers HBM latency)
        float qn = 0.f, knx = 0.f, vn = 0.f, an = 0.f;
        if (t < TT - 1){
            qn = (float)pq[1024]; knx = (float)pk[1024];
            vn = (float)pv[1024]; an  = (float)pa[1024];
        }
        const float bt = bp[t];

        const float nk  = allreduce64(kv * kv);
        const float kni = kv / fmaxf(sqrtf(nk), 1e-12f);

        pack[lane] = make_float4(kni, av, qv, 0.0f);
        __builtin_amdgcn_wave_barrier();

        // fused: M update + Mk (row-local)  |  S row-scale + kproj (col-local)
        float mk = 0.0f, kp = 0.0f;
        #pragma unroll
        for (int j = 0; j < 64; ++j){
            const float2 pj = *(const float2*)&pack[j];   // {kn[j], a[j]} broadcast
            m[j] = gm * m[j] + kni * pj.x;
            mk  += m[j] * pj.x;
            s[j] *= pj.y;
            kp  += pj.x * s[j];
        }
        __builtin_amdgcn_wave_barrier();

        const float nmk = allreduce64(mk * mk);
        const float kt  = mk / fmaxf(sqrtf(nmk), 1e-6f);
        pack[lane].w = kt;
        __builtin_amdgcn_wave_barrier();

        // S -= b*ktld⊗kproj ; S += b*kn⊗v ; o = S^T q  (all col-local)
        const float c1 = bt * kp;
        const float c2 = bt * vv;
        float o = 0.0f;
        #pragma unroll
        for (int d = 0; d < 64; ++d){
            const float4 pd = pack[d];                    // {kn,a,q,ktld} broadcast
            float sd = s[d];
            sd = fmaf(-pd.w, c1, sd);
            sd = fmaf(pd.x, c2, sd);
            s[d] = sd;
            o = fmaf(sd, pd.z, o);
        }
        __builtin_amdgcn_wave_barrier();

        op[(size_t)t * 1024] = (f16)o;

        pq += 1024; pk += 1024; pv += 1024; pa += 1024;
        qv = qn; kv = knx; vv = vn; av = an;
    }
}

// ---------------- workspace layout (bytes), total ~107 MB ----------------
// Q,K (fp16, 32 MB each) live inside d_out (64 MB f32 out buffer, dead until final GEMM).
// xn slot is reused for the scan output O (both fp16 32 MB; xn dead after beta+gemm<0>).
#define OFF_XN    ((size_t)0)                     // 16384*1024 f16 = 32 MB  (later: O)
#define OFF_WCAT  ((size_t)33554432)              // 4*1024*1024 f16 = 8 MB
#define OFF_WOT   ((size_t)41943040)              // 1024*1024 f16  =  2 MB
#define OFF_BETA  ((size_t)44040192)              // 128*2048 f32   =  1 MB
#define OFF_V     ((size_t)45088768)              // 16384*1024 f16 = 32 MB
#define OFF_A     ((size_t)78643200)              // 16384*1024 f16 = 32 MB
#define WS_NEED   ((size_t)112197632)

extern "C" void kernel_launch(void* const* d_in, const int* in_sizes, int n_in,
                              void* d_out, int out_size, void* d_ws, size_t ws_size,
                              hipStream_t stream)
{
    const float* x   = (const float*)d_in[0];
    const float* lng = (const float*)d_in[1];
    const float* lnb = (const float*)d_in[2];
    const float* Wq  = (const float*)d_in[3];
    const float* Wk  = (const float*)d_in[4];
    const float* Wv  = (const float*)d_in[5];
    const float* Wa  = (const float*)d_in[6];
    const float* ba  = (const float*)d_in[7];
    const float* Wb  = (const float*)d_in[8];
    const float* bb  = (const float*)d_in[9];
    const float* rgm = (const float*)d_in[10];
    const float* Wo  = (const float*)d_in[11];
    float* out = (float*)d_out;

    if (ws_size < WS_NEED){
        // Unmistakable diagnostic: error ~1.2e4 means "workspace too small", vs 10.0 = "never wrote"
        sentinel_fill<<<(out_size + 255) / 256, 256, 0, stream>>>(out, out_size);
        return;
    }

    char* ws = (char*)d_ws;
    f16*   xn   = (f16*)(ws + OFF_XN);
    f16*   wcat = (f16*)(ws + OFF_WCAT);
    f16*   wot  = (f16*)(ws + OFF_WOT);
    float* betw = (float*)(ws + OFF_BETA);
    f16*   Vbuf = (f16*)(ws + OFF_V);
    f16*   Abuf = (f16*)(ws + OFF_A);
    f16*   Qbuf = (f16*)d_out;                    // 32 MB
    f16*   Kbuf = Qbuf + (size_t)16384 * 1024;    // 32 MB (d_out total = 64 MB)
    f16*   Obuf = xn;                             // reuse xn slot after it's dead

    ln_kernel<<<16384, 256, 0, stream>>>(x, lng, lnb, xn);
    transpose5<<<dim3(32, 32, 5), dim3(32, 8), 0, stream>>>(Wq, Wk, Wv, Wa, Wo, wcat, wot);
    gemm_bt<0><<<dim3(128, 32), 256, 0, stream>>>(xn, wcat, 16384, 4096, 1024,
                                                  ba, nullptr, nullptr, Qbuf, Kbuf, Vbuf, Abuf);
    beta_kernel<<<16384, 256, 0, stream>>>(xn, Wb, bb, betw);
    scan_kernel<<<128, 64, 0, stream>>>(Qbuf, Kbuf, Vbuf, Abuf, betw, rgm, Obuf);
    gemm_bt<1><<<dim3(128, 8), 256, 0, stream>>>(Obuf, wot, 16384, 1024, 1024,
                                                 nullptr, x, out, nullptr, nullptr, nullptr, nullptr);
}

// Round 3
// 3501.711 us; speedup vs baseline: 2.1556x; 2.1556x over previous
//
#include <hip/hip_runtime.h>

typedef unsigned short u16;
typedef unsigned int   u32;
typedef _Float16       f16;
typedef __attribute__((ext_vector_type(4))) _Float16 v4h;
typedef __attribute__((ext_vector_type(8))) _Float16 v8h;   // MFMA A/B frag (4 VGPRs)
typedef __attribute__((ext_vector_type(4))) float    v4f;   // MFMA C/D frag

#define TT 2048
#define BB 8

static __device__ __forceinline__ float sigmoidf_(float x){
    return 1.0f / (1.0f + __expf(-x));
}
static __device__ __forceinline__ float allreduce64(float v){
    #pragma unroll
    for (int off = 32; off > 0; off >>= 1) v += __shfl_xor(v, off, 64);
    return v;
}

// ---------------- diagnostic: fills d_out with sentinel if ws too small ----------------
__global__ __launch_bounds__(256) void sentinel_fill(float* __restrict__ out, int n){
    int i = blockIdx.x * 256 + threadIdx.x;
    if (i < n) out[i] = 12345.0f;
}

// ---------------- LayerNorm: x (16384x1024 f32) -> xn (fp16) ----------------
__global__ __launch_bounds__(256) void ln_kernel(
    const float* __restrict__ x, const float* __restrict__ g,
    const float* __restrict__ bta, f16* __restrict__ xn)
{
    const int row = blockIdx.x;
    const int tid = threadIdx.x;
    const float4 v = ((const float4*)(x + (size_t)row * 1024))[tid];
    float s  = v.x + v.y + v.z + v.w;
    float s2 = v.x*v.x + v.y*v.y + v.z*v.z + v.w*v.w;
    #pragma unroll
    for (int off = 32; off > 0; off >>= 1){
        s  += __shfl_xor(s,  off, 64);
        s2 += __shfl_xor(s2, off, 64);
    }
    __shared__ float rs[4], rq[4];
    const int wv = tid >> 6, lane = tid & 63;
    if (lane == 0){ rs[wv] = s; rq[wv] = s2; }
    __syncthreads();
    s  = rs[0] + rs[1] + rs[2] + rs[3];
    s2 = rq[0] + rq[1] + rq[2] + rq[3];
    const float mu   = s * (1.0f / 1024.0f);
    const float var  = s2 * (1.0f / 1024.0f) - mu * mu;
    const float rstd = rsqrtf(var + 1e-5f);
    const float4 gv = ((const float4*)g)[tid];
    const float4 bv = ((const float4*)bta)[tid];
    v4h o;
    o.x = (f16)((v.x - mu) * rstd * gv.x + bv.x);
    o.y = (f16)((v.y - mu) * rstd * gv.y + bv.y);
    o.z = (f16)((v.z - mu) * rstd * gv.z + bv.z);
    o.w = (f16)((v.w - mu) * rstd * gv.w + bv.w);
    ((v4h*)(xn + (size_t)row * 1024))[tid] = o;
}

// ------- transpose+cast 5 weight mats (1024x1024 f32, [k][n]) -> fp16 [n][k] -------
__global__ __launch_bounds__(256) void transpose5(
    const float* __restrict__ Wq, const float* __restrict__ Wk,
    const float* __restrict__ Wv, const float* __restrict__ Wa,
    const float* __restrict__ Wo, f16* __restrict__ wcat, f16* __restrict__ wot)
{
    __shared__ float tile[32][33];
    const int z = blockIdx.z;
    const float* src = (z==0)?Wq:(z==1)?Wk:(z==2)?Wv:(z==3)?Wa:Wo;
    f16* dst = (z < 4) ? (wcat + (size_t)z * 1024 * 1024) : wot;
    const int bx = blockIdx.x * 32, by = blockIdx.y * 32;
    const int tx = threadIdx.x, ty = threadIdx.y;
    #pragma unroll
    for (int i = 0; i < 4; ++i)
        tile[ty + i*8][tx] = src[(size_t)(by + ty + i*8) * 1024 + bx + tx];
    __syncthreads();
    #pragma unroll
    for (int i = 0; i < 4; ++i)
        dst[(size_t)(bx + ty + i*8) * 1024 + by + tx] = (f16)tile[tx][ty + i*8];
}

// ---------------- fp16 MFMA GEMM, B transposed (N x K). BM=BN=128, BK=64 ----------------
template<int MODE>
__global__ __launch_bounds__(256) void gemm_bt(
    const f16* __restrict__ A, const f16* __restrict__ Bt,
    int M, int N, int K,
    const float* __restrict__ ba, const float* __restrict__ resid,
    float* __restrict__ Cf,
    f16* __restrict__ Qb, f16* __restrict__ Kb,
    f16* __restrict__ Vb, f16* __restrict__ Ab)
{
    __shared__ f16 As[128 * 72];
    __shared__ f16 Bs[128 * 72];
    const int tid = threadIdx.x;
    const int bm = blockIdx.x, bn = blockIdx.y;
    const int wv = tid >> 6, lane = tid & 63;
    const int l15 = lane & 15, quad = lane >> 4;
    const int mb = (wv >> 1) * 64, nb = (wv & 1) * 64;
    v4f acc[4][4];
    const v4f vzero = {0.0f, 0.0f, 0.0f, 0.0f};
    #pragma unroll
    for (int i = 0; i < 4; ++i)
        #pragma unroll
        for (int j = 0; j < 4; ++j) acc[i][j] = vzero;

    const f16* Ag = A  + (size_t)bm * 128 * K;
    const f16* Bg = Bt + (size_t)bn * 128 * K;

    for (int k0 = 0; k0 < K; k0 += 64){
        __syncthreads();
        #pragma unroll
        for (int it = 0; it < 4; ++it){
            const int ch = tid + it * 256;
            const int r = ch >> 3, c = ch & 7;
            const uint4 da = *(const uint4*)(Ag + (size_t)r * K + k0 + c * 8);
            *(uint4*)(&As[r * 72 + c * 8]) = da;
            const uint4 db = *(const uint4*)(Bg + (size_t)r * K + k0 + c * 8);
            *(uint4*)(&Bs[r * 72 + c * 8]) = db;
        }
        __syncthreads();
        #pragma unroll
        for (int kk = 0; kk < 2; ++kk){
            v8h af[4], bfr[4];
            #pragma unroll
            for (int i = 0; i < 4; ++i){
                af[i]  = *(const v8h*)(&As[(mb + i*16 + l15) * 72 + kk*32 + quad*8]);
                bfr[i] = *(const v8h*)(&Bs[(nb + i*16 + l15) * 72 + kk*32 + quad*8]);
            }
            #pragma unroll
            for (int i = 0; i < 4; ++i)
                #pragma unroll
                for (int j = 0; j < 4; ++j)
                    acc[i][j] = __builtin_amdgcn_mfma_f32_16x16x32_f16(af[i], bfr[j], acc[i][j], 0, 0, 0);
        }
    }
    const int seg = (bn * 128) >> 10;
    f16* dst = (seg == 0) ? Qb : (seg == 1) ? Kb : (seg == 2) ? Vb : Ab;
    #pragma unroll
    for (int i = 0; i < 4; ++i){
        #pragma unroll
        for (int j = 0; j < 4; ++j){
            const int col = bn * 128 + nb + j * 16 + l15;
            const int c   = col & 1023;
            #pragma unroll
            for (int r = 0; r < 4; ++r){
                const int row = bm * 128 + mb + i * 16 + quad * 4 + r;
                float val = acc[i][j][r];
                if (MODE == 0){
                    if (seg == 3) val = sigmoidf_(val + ba[c]);
                    dst[(size_t)row * 1024 + c] = (f16)val;
                } else {
                    Cf[(size_t)row * N + col] = val + resid[(size_t)row * N + col];
                }
            }
        }
    }
}

// ---------------- beta: sigmoid(xn @ Wb + bb), stored chain-major [b*16+h][t] ----------------
__global__ __launch_bounds__(256) void beta_kernel(
    const f16* __restrict__ xn, const float* __restrict__ Wb,
    const float* __restrict__ bb, float* __restrict__ betaw)
{
    const int row = blockIdx.x;
    const int b = row >> 11, t = row & 2047;
    const int wv = threadIdx.x >> 6, lane = threadIdx.x & 63;
    const f16* xr = xn + (size_t)row * 1024;
    #pragma unroll
    for (int hh = 0; hh < 4; ++hh){
        const int h = wv * 4 + hh;
        float acc = 0.0f;
        #pragma unroll 4
        for (int k = lane; k < 1024; k += 64)
            acc += (float)xr[k] * Wb[k * 16 + h];
        acc = allreduce64(acc);
        if (lane == 0)
            betaw[((size_t)(b * 16 + h)) * 2048 + t] = sigmoidf_(acc + bb[h]);
    }
}

// ---------------- sequential scan v2: 4 waves per (b,h) chain ----------------
// M is symmetric (M=gm*M+kn kn^T preserves symmetry; M0=eps*I), so Mk is computable
// column-locally like S: thread (w,l) owns M[16w+dd][l] and S[16w+dd][l], dd in [0,16).
// Per step: phase A (M update + mk partial, S row-scale + kproj partial) -> cross-wave
// reduce -> k_tilde (redundant per-wave allreduce) -> phase B (S delta update + o partial)
// -> cross-wave reduce -> output. Broadcasts = same-address b128 LDS reads (conflict-free).
// q/k/v/a/beta staged in 16-step LDS tiles; outputs buffered in LDS -> one vmcnt drain
// per 16 steps instead of per barrier.
#define SC 16
__global__ __launch_bounds__(256, 1) void scan_kernel(
    const f16* __restrict__ Qb, const f16* __restrict__ Kb,
    const f16* __restrict__ Vb, const f16* __restrict__ Ab,
    const float* __restrict__ beta, const float* __restrict__ rgm,
    f16* __restrict__ O)
{
    const int chain = blockIdx.x;           // b*16 + h
    const int b = chain >> 4, h = chain & 15;
    const int tid = threadIdx.x;
    const int w = tid >> 6, l = tid & 63;
    const float gm = sigmoidf_(rgm[h]);

    __shared__ f16 tQ[SC * 64], tK[SC * 64], tV[SC * 64], tA[SC * 64];
    __shared__ f16 oT[SC * 64];
    __shared__ float betaT[SC];
    __shared__ __align__(16) float2 pka[64];   // {kn, a}
    __shared__ __align__(16) float2 pkb[64];   // {ktld, q}
    __shared__ __align__(16) float2 redA[256]; // {mk partial, kproj partial}
    __shared__ float redO[256];

    float m[SC], s[SC];
    #pragma unroll
    for (int dd = 0; dd < SC; ++dd){
        m[dd] = (w * 16 + dd == l) ? 1e-6f : 0.0f;  // M0 = EPS*I
        s[dd] = 0.0f;
    }

    const size_t cbase = ((size_t)(b * TT)) * 1024 + h * 64;
    const int r = tid >> 2, j4 = tid & 3;          // staging: row r (tensor,step), 32B chunk j4
    const int tens = r >> 4, str = r & 15;
    const f16* sg = (tens == 0) ? Qb : (tens == 1) ? Kb : (tens == 2) ? Vb : Ab;
    f16* sl = (tens == 0) ? tQ : (tens == 1) ? tK : (tens == 2) ? tV : tA;
    const int ftt = tid >> 4, fj = tid & 15;       // flush: step ftt, 8B chunk fj

    for (int t0 = 0; t0 < TT; t0 += SC){
        // ---- stage 16 steps of q/k/v/a (+beta) into LDS ----
        {
            const uint4* gp = (const uint4*)(sg + cbase + (size_t)(t0 + str) * 1024 + j4 * 16);
            const uint4 d0 = gp[0], d1 = gp[1];
            *(uint4*)(sl + str * 64 + j4 * 16)     = d0;
            *(uint4*)(sl + str * 64 + j4 * 16 + 8) = d1;
            if (tid < SC) betaT[tid] = beta[(size_t)chain * TT + t0 + tid];
        }
        __syncthreads();

        for (int tt = 0; tt < SC; ++tt){
            if (w == 1){
                const float kv = (float)tK[tt * 64 + l];
                const float nk = allreduce64(kv * kv);
                const float kni = kv / fmaxf(sqrtf(nk), 1e-12f);
                const float av = (float)tA[tt * 64 + l];
                pka[l] = make_float2(kni, av);
            }
            __syncthreads();                               // B1
            const float knl = pka[l].x;
            const float vv = (float)tV[tt * 64 + l];
            const float qv = (float)tQ[tt * 64 + l];
            float kn16[SC];
            float mk0 = 0.f, mk1 = 0.f, kp0 = 0.f, kp1 = 0.f;
            #pragma unroll
            for (int dd = 0; dd < SC; dd += 2){
                const float4 pr = *(const float4*)&pka[w * 16 + dd];  // {kn,a,kn',a'} broadcast
                kn16[dd] = pr.x; kn16[dd + 1] = pr.z;
                m[dd] = gm * m[dd] + knl * pr.x;
                mk0 = fmaf(m[dd], pr.x, mk0);
                s[dd] *= pr.y;
                kp0 = fmaf(pr.x, s[dd], kp0);
                m[dd + 1] = gm * m[dd + 1] + knl * pr.z;
                mk1 = fmaf(m[dd + 1], pr.z, mk1);
                s[dd + 1] *= pr.w;
                kp1 = fmaf(pr.z, s[dd + 1], kp1);
            }
            redA[w * 64 + l] = make_float2(mk0 + mk1, kp0 + kp1);
            __syncthreads();                               // B2
            const float2 r0 = redA[l], r1 = redA[64 + l], r2 = redA[128 + l], r3 = redA[192 + l];
            const float mk = r0.x + r1.x + r2.x + r3.x;
            const float nmk = allreduce64(mk * mk);
            const float ktl = mk / fmaxf(sqrtf(nmk), 1e-6f);
            const float kproj = r0.y + r1.y + r2.y + r3.y;
            const float bt = betaT[tt];
            const float c1 = bt * kproj, c2 = bt * vv;
            if (w == 2) pkb[l] = make_float2(ktl, qv);
            __syncthreads();                               // B3
            float o0 = 0.f, o1 = 0.f;
            #pragma unroll
            for (int dd = 0; dd < SC; dd += 2){
                const float4 pr = *(const float4*)&pkb[w * 16 + dd];  // {kt,q,kt',q'} broadcast
                const float s0 = s[dd] - pr.x * c1 + kn16[dd] * c2;
                s[dd] = s0; o0 = fmaf(s0, pr.y, o0);
                const float s1 = s[dd + 1] - pr.z * c1 + kn16[dd + 1] * c2;
                s[dd + 1] = s1; o1 = fmaf(s1, pr.w, o1);
            }
            redO[w * 64 + l] = o0 + o1;
            __syncthreads();                               // B4
            if (w == 0){
                const float o = redO[l] + redO[64 + l] + redO[128 + l] + redO[192 + l];
                oT[tt * 64 + l] = (f16)o;
            }
        }
        __syncthreads();   // oT complete; tile arrays free for restage
        {
            const uint2 d = *(const uint2*)(oT + ftt * 64 + fj * 4);
            *(uint2*)(O + cbase + (size_t)(t0 + ftt) * 1024 + fj * 4) = d;
        }
    }
}

// ---------------- workspace layout (bytes), total ~107 MB ----------------
#define OFF_XN    ((size_t)0)                     // 16384*1024 f16 = 32 MB  (later: O)
#define OFF_WCAT  ((size_t)33554432)              // 4*1024*1024 f16 = 8 MB
#define OFF_WOT   ((size_t)41943040)              // 1024*1024 f16  =  2 MB
#define OFF_BETA  ((size_t)44040192)              // 128*2048 f32   =  1 MB
#define OFF_V     ((size_t)45088768)              // 16384*1024 f16 = 32 MB
#define OFF_A     ((size_t)78643200)              // 16384*1024 f16 = 32 MB
#define WS_NEED   ((size_t)112197632)

extern "C" void kernel_launch(void* const* d_in, const int* in_sizes, int n_in,
                              void* d_out, int out_size, void* d_ws, size_t ws_size,
                              hipStream_t stream)
{
    const float* x   = (const float*)d_in[0];
    const float* lng = (const float*)d_in[1];
    const float* lnb = (const float*)d_in[2];
    const float* Wq  = (const float*)d_in[3];
    const float* Wk  = (const float*)d_in[4];
    const float* Wv  = (const float*)d_in[5];
    const float* Wa  = (const float*)d_in[6];
    const float* ba  = (const float*)d_in[7];
    const float* Wb  = (const float*)d_in[8];
    const float* bb  = (const float*)d_in[9];
    const float* rgm = (const float*)d_in[10];
    const float* Wo  = (const float*)d_in[11];
    float* out = (float*)d_out;

    if (ws_size < WS_NEED){
        sentinel_fill<<<(out_size + 255) / 256, 256, 0, stream>>>(out, out_size);
        return;
    }

    char* ws = (char*)d_ws;
    f16*   xn   = (f16*)(ws + OFF_XN);
    f16*   wcat = (f16*)(ws + OFF_WCAT);
    f16*   wot  = (f16*)(ws + OFF_WOT);
    float* betw = (float*)(ws + OFF_BETA);
    f16*   Vbuf = (f16*)(ws + OFF_V);
    f16*   Abuf = (f16*)(ws + OFF_A);
    f16*   Qbuf = (f16*)d_out;                    // 32 MB
    f16*   Kbuf = Qbuf + (size_t)16384 * 1024;    // 32 MB (d_out total = 64 MB)
    f16*   Obuf = xn;                             // reuse xn slot after it's dead

    ln_kernel<<<16384, 256, 0, stream>>>(x, lng, lnb, xn);
    transpose5<<<dim3(32, 32, 5), dim3(32, 8), 0, stream>>>(Wq, Wk, Wv, Wa, Wo, wcat, wot);
    gemm_bt<0><<<dim3(128, 32), 256, 0, stream>>>(xn, wcat, 16384, 4096, 1024,
                                                  ba, nullptr, nullptr, Qbuf, Kbuf, Vbuf, Abuf);
    beta_kernel<<<16384, 256, 0, stream>>>(xn, Wb, bb, betw);
    scan_kernel<<<128, 256, 0, stream>>>(Qbuf, Kbuf, Vbuf, Abuf, betw, rgm, Obuf);
    gemm_bt<1><<<dim3(128, 8), 256, 0, stream>>>(Obuf, wot, 16384, 1024, 1024,
                                                 nullptr, x, out, nullptr, nullptr, nullptr, nullptr);
}

// Round 4
// 2586.327 us; speedup vs baseline: 2.9186x; 1.3539x over previous
//
#include <hip/hip_runtime.h>

typedef unsigned short u16;
typedef unsigned int   u32;
typedef _Float16       f16;
typedef __attribute__((ext_vector_type(4))) _Float16 v4h;
typedef __attribute__((ext_vector_type(8))) _Float16 v8h;   // MFMA A/B frag (4 VGPRs)
typedef __attribute__((ext_vector_type(4))) float    v4f;   // MFMA C/D frag

#define TT 2048
#define BB 8

static __device__ __forceinline__ float sigmoidf_(float x){
    return 1.0f / (1.0f + __expf(-x));
}
static __device__ __forceinline__ float allreduce64(float v){
    #pragma unroll
    for (int off = 32; off > 0; off >>= 1) v += __shfl_xor(v, off, 64);
    return v;
}

// Wave64 sum via DPP (VALU-only, ~50 cyc vs ~700 for ds_swizzle chain).
// row_shr 1/2/4/8 builds row sums in lanes 15/31/47/63; row_bcast:15 then
// row_bcast:31 accumulate rows; lane 63 holds the total; readlane broadcasts.
static __device__ __forceinline__ float wave_sum64(float x){
    int t;
    t = __builtin_amdgcn_update_dpp(0, __float_as_int(x), 0x111, 0xf, 0xf, true); x += __int_as_float(t);
    t = __builtin_amdgcn_update_dpp(0, __float_as_int(x), 0x112, 0xf, 0xf, true); x += __int_as_float(t);
    t = __builtin_amdgcn_update_dpp(0, __float_as_int(x), 0x114, 0xf, 0xf, true); x += __int_as_float(t);
    t = __builtin_amdgcn_update_dpp(0, __float_as_int(x), 0x118, 0xf, 0xf, true); x += __int_as_float(t);
    t = __builtin_amdgcn_update_dpp(0, __float_as_int(x), 0x142, 0xf, 0xf, true); x += __int_as_float(t);
    t = __builtin_amdgcn_update_dpp(0, __float_as_int(x), 0x143, 0xf, 0xf, true); x += __int_as_float(t);
    return __int_as_float(__builtin_amdgcn_readlane(__float_as_int(x), 63));
}
static __device__ __forceinline__ float rlane(float v, int lane){
    return __int_as_float(__builtin_amdgcn_readlane(__float_as_int(v), lane));
}

// ---------------- diagnostic: fills d_out with sentinel if ws too small ----------------
__global__ __launch_bounds__(256) void sentinel_fill(float* __restrict__ out, int n){
    int i = blockIdx.x * 256 + threadIdx.x;
    if (i < n) out[i] = 12345.0f;
}

// ---------------- LayerNorm: x (16384x1024 f32) -> xn (fp16) ----------------
__global__ __launch_bounds__(256) void ln_kernel(
    const float* __restrict__ x, const float* __restrict__ g,
    const float* __restrict__ bta, f16* __restrict__ xn)
{
    const int row = blockIdx.x;
    const int tid = threadIdx.x;
    const float4 v = ((const float4*)(x + (size_t)row * 1024))[tid];
    float s  = v.x + v.y + v.z + v.w;
    float s2 = v.x*v.x + v.y*v.y + v.z*v.z + v.w*v.w;
    #pragma unroll
    for (int off = 32; off > 0; off >>= 1){
        s  += __shfl_xor(s,  off, 64);
        s2 += __shfl_xor(s2, off, 64);
    }
    __shared__ float rs[4], rq[4];
    const int wv = tid >> 6, lane = tid & 63;
    if (lane == 0){ rs[wv] = s; rq[wv] = s2; }
    __syncthreads();
    s  = rs[0] + rs[1] + rs[2] + rs[3];
    s2 = rq[0] + rq[1] + rq[2] + rq[3];
    const float mu   = s * (1.0f / 1024.0f);
    const float var  = s2 * (1.0f / 1024.0f) - mu * mu;
    const float rstd = rsqrtf(var + 1e-5f);
    const float4 gv = ((const float4*)g)[tid];
    const float4 bv = ((const float4*)bta)[tid];
    v4h o;
    o.x = (f16)((v.x - mu) * rstd * gv.x + bv.x);
    o.y = (f16)((v.y - mu) * rstd * gv.y + bv.y);
    o.z = (f16)((v.z - mu) * rstd * gv.z + bv.z);
    o.w = (f16)((v.w - mu) * rstd * gv.w + bv.w);
    ((v4h*)(xn + (size_t)row * 1024))[tid] = o;
}

// ------- transpose+cast 5 weight mats (1024x1024 f32, [k][n]) -> fp16 [n][k] -------
__global__ __launch_bounds__(256) void transpose5(
    const float* __restrict__ Wq, const float* __restrict__ Wk,
    const float* __restrict__ Wv, const float* __restrict__ Wa,
    const float* __restrict__ Wo, f16* __restrict__ wcat, f16* __restrict__ wot)
{
    __shared__ float tile[32][33];
    const int z = blockIdx.z;
    const float* src = (z==0)?Wq:(z==1)?Wk:(z==2)?Wv:(z==3)?Wa:Wo;
    f16* dst = (z < 4) ? (wcat + (size_t)z * 1024 * 1024) : wot;
    const int bx = blockIdx.x * 32, by = blockIdx.y * 32;
    const int tx = threadIdx.x, ty = threadIdx.y;
    #pragma unroll
    for (int i = 0; i < 4; ++i)
        tile[ty + i*8][tx] = src[(size_t)(by + ty + i*8) * 1024 + bx + tx];
    __syncthreads();
    #pragma unroll
    for (int i = 0; i < 4; ++i)
        dst[(size_t)(bx + ty + i*8) * 1024 + by + tx] = (f16)tile[tx][ty + i*8];
}

// ---------------- fp16 MFMA GEMM, B transposed (N x K). BM=BN=128, BK=64 ----------------
template<int MODE>
__global__ __launch_bounds__(256) void gemm_bt(
    const f16* __restrict__ A, const f16* __restrict__ Bt,
    int M, int N, int K,
    const float* __restrict__ ba, const float* __restrict__ resid,
    float* __restrict__ Cf,
    f16* __restrict__ Qb, f16* __restrict__ Kb,
    f16* __restrict__ Vb, f16* __restrict__ Ab)
{
    __shared__ f16 As[128 * 72];
    __shared__ f16 Bs[128 * 72];
    const int tid = threadIdx.x;
    const int bm = blockIdx.x, bn = blockIdx.y;
    const int wv = tid >> 6, lane = tid & 63;
    const int l15 = lane & 15, quad = lane >> 4;
    const int mb = (wv >> 1) * 64, nb = (wv & 1) * 64;
    v4f acc[4][4];
    const v4f vzero = {0.0f, 0.0f, 0.0f, 0.0f};
    #pragma unroll
    for (int i = 0; i < 4; ++i)
        #pragma unroll
        for (int j = 0; j < 4; ++j) acc[i][j] = vzero;

    const f16* Ag = A  + (size_t)bm * 128 * K;
    const f16* Bg = Bt + (size_t)bn * 128 * K;

    for (int k0 = 0; k0 < K; k0 += 64){
        __syncthreads();
        #pragma unroll
        for (int it = 0; it < 4; ++it){
            const int ch = tid + it * 256;
            const int r = ch >> 3, c = ch & 7;
            const uint4 da = *(const uint4*)(Ag + (size_t)r * K + k0 + c * 8);
            *(uint4*)(&As[r * 72 + c * 8]) = da;
            const uint4 db = *(const uint4*)(Bg + (size_t)r * K + k0 + c * 8);
            *(uint4*)(&Bs[r * 72 + c * 8]) = db;
        }
        __syncthreads();
        #pragma unroll
        for (int kk = 0; kk < 2; ++kk){
            v8h af[4], bfr[4];
            #pragma unroll
            for (int i = 0; i < 4; ++i){
                af[i]  = *(const v8h*)(&As[(mb + i*16 + l15) * 72 + kk*32 + quad*8]);
                bfr[i] = *(const v8h*)(&Bs[(nb + i*16 + l15) * 72 + kk*32 + quad*8]);
            }
            #pragma unroll
            for (int i = 0; i < 4; ++i)
                #pragma unroll
                for (int j = 0; j < 4; ++j)
                    acc[i][j] = __builtin_amdgcn_mfma_f32_16x16x32_f16(af[i], bfr[j], acc[i][j], 0, 0, 0);
        }
    }
    const int seg = (bn * 128) >> 10;
    f16* dst = (seg == 0) ? Qb : (seg == 1) ? Kb : (seg == 2) ? Vb : Ab;
    #pragma unroll
    for (int i = 0; i < 4; ++i){
        #pragma unroll
        for (int j = 0; j < 4; ++j){
            const int col = bn * 128 + nb + j * 16 + l15;
            const int c   = col & 1023;
            #pragma unroll
            for (int r = 0; r < 4; ++r){
                const int row = bm * 128 + mb + i * 16 + quad * 4 + r;
                float val = acc[i][j][r];
                if (MODE == 0){
                    if (seg == 3) val = sigmoidf_(val + ba[c]);
                    dst[(size_t)row * 1024 + c] = (f16)val;
                } else {
                    Cf[(size_t)row * N + col] = val + resid[(size_t)row * N + col];
                }
            }
        }
    }
}

// ---------------- beta: sigmoid(xn @ Wb + bb), stored chain-major [b*16+h][t] ----------------
__global__ __launch_bounds__(256) void beta_kernel(
    const f16* __restrict__ xn, const float* __restrict__ Wb,
    const float* __restrict__ bb, float* __restrict__ betaw)
{
    const int row = blockIdx.x;
    const int b = row >> 11, t = row & 2047;
    const int wv = threadIdx.x >> 6, lane = threadIdx.x & 63;
    const f16* xr = xn + (size_t)row * 1024;
    #pragma unroll
    for (int hh = 0; hh < 4; ++hh){
        const int h = wv * 4 + hh;
        float acc = 0.0f;
        #pragma unroll 4
        for (int k = lane; k < 1024; k += 64)
            acc += (float)xr[k] * Wb[k * 16 + h];
        acc = allreduce64(acc);
        if (lane == 0)
            betaw[((size_t)(b * 16 + h)) * 2048 + t] = sigmoidf_(acc + bb[h]);
    }
}

// ---------------- sequential scan v3: 4 waves per chain, 1 barrier/step ----------------
// Thread (w,l) owns M[16w+dd][l], S[16w+dd][l]. Row-vector broadcasts (kn, a, ktld, q)
// via v_readlane at wave-uniform indices 16w+dd (no LDS, no barrier). Both vector norms
// computed redundantly per wave via DPP reduction (VALU-only). Cross-wave mk/kproj
// exchange is the single per-step barrier (redA double-buffered on tt&1). o partials go
// to per-wave private oTw buffers, reduced once per 16-step tile.
#define SC 16
__global__ __launch_bounds__(256, 1) void scan_kernel(
    const f16* __restrict__ Qb, const f16* __restrict__ Kb,
    const f16* __restrict__ Vb, const f16* __restrict__ Ab,
    const float* __restrict__ beta, const float* __restrict__ rgm,
    f16* __restrict__ O)
{
    const int chain = blockIdx.x;           // b*16 + h
    const int b = chain >> 4, h = chain & 15;
    const int tid = threadIdx.x;
    const int w = __builtin_amdgcn_readfirstlane(tid) >> 6;   // provably wave-uniform
    const int l = tid & 63;
    const int jbase = w << 4;
    const float gm = sigmoidf_(rgm[h]);

    __shared__ f16 tQ[SC * 64], tK[SC * 64], tV[SC * 64], tA[SC * 64];
    __shared__ float betaT[SC];
    __shared__ __align__(16) float2 redA[2][256]; // {mk partial, kproj partial}, dbuf on tt&1
    __shared__ float oTw[4][SC * 64];             // per-wave private o partials

    float m[SC], s[SC];
    #pragma unroll
    for (int dd = 0; dd < SC; ++dd){
        m[dd] = (jbase + dd == l) ? 1e-6f : 0.0f;  // M0 = EPS*I
        s[dd] = 0.0f;
    }

    const size_t cbase = ((size_t)(b * TT)) * 1024 + h * 64;
    const int r = tid >> 2, j4 = tid & 3;          // staging: row r (tensor,step), 32B chunk j4
    const int tens = r >> 4, str = r & 15;
    const f16* sg = (tens == 0) ? Qb : (tens == 1) ? Kb : (tens == 2) ? Vb : Ab;
    f16* sl = (tens == 0) ? tQ : (tens == 1) ? tK : (tens == 2) ? tV : tA;

    for (int t0 = 0; t0 < TT; t0 += SC){
        // ---- stage 16 steps of q/k/v/a (+beta) into LDS ----
        {
            const uint4* gp = (const uint4*)(sg + cbase + (size_t)(t0 + str) * 1024 + j4 * 16);
            const uint4 d0 = gp[0], d1 = gp[1];
            *(uint4*)(sl + str * 64 + j4 * 16)     = d0;
            *(uint4*)(sl + str * 64 + j4 * 16 + 8) = d1;
            if (tid < SC) betaT[tid] = beta[(size_t)chain * TT + t0 + tid];
        }
        __syncthreads();   // T1: tiles ready (also orders prior-tile oTw reads vs phase-B writes)

        for (int tt = 0; tt < SC; ++tt){
            // per-lane loads (column l of step tt)
            const float kvf = (float)tK[tt * 64 + l];
            const float av  = (float)tA[tt * 64 + l];
            const float qv  = (float)tQ[tt * 64 + l];
            const float vv  = (float)tV[tt * 64 + l];

            // kn = k/max(||k||,1e-12), redundant on every wave (DPP, VALU-only)
            const float nk  = wave_sum64(kvf * kvf);
            const float kni = kvf * __builtin_amdgcn_rcpf(fmaxf(sqrtf(nk), 1e-12f));

            // wave-row broadcasts via readlane (SGPR results)
            float knj[SC], aj[SC];
            #pragma unroll
            for (int dd = 0; dd < SC; ++dd){
                knj[dd] = rlane(kni, jbase + dd);
                aj[dd]  = rlane(av,  jbase + dd);
            }

            // phase A: M update + mk partial; S row-scale + kproj partial
            float mk0 = 0.f, mk1 = 0.f, kp0 = 0.f, kp1 = 0.f;
            #pragma unroll
            for (int dd = 0; dd < SC; dd += 2){
                const float t0m = kni * knj[dd];
                m[dd] = fmaf(gm, m[dd], t0m);
                mk0 = fmaf(m[dd], knj[dd], mk0);
                s[dd] *= aj[dd];
                kp0 = fmaf(knj[dd], s[dd], kp0);
                const float t1m = kni * knj[dd + 1];
                m[dd + 1] = fmaf(gm, m[dd + 1], t1m);
                mk1 = fmaf(m[dd + 1], knj[dd + 1], mk1);
                s[dd + 1] *= aj[dd + 1];
                kp1 = fmaf(knj[dd + 1], s[dd + 1], kp1);
            }
            redA[tt & 1][(w << 6) + l] = make_float2(mk0 + mk1, kp0 + kp1);
            __syncthreads();                               // the one per-step barrier

            const float2 r0 = redA[tt & 1][l];
            const float2 r1 = redA[tt & 1][64 + l];
            const float2 r2 = redA[tt & 1][128 + l];
            const float2 r3 = redA[tt & 1][192 + l];
            const float mkf   = r0.x + r1.x + r2.x + r3.x;
            const float kproj = r0.y + r1.y + r2.y + r3.y;
            const float nmk = wave_sum64(mkf * mkf);
            const float ktl = mkf * __builtin_amdgcn_rcpf(fmaxf(sqrtf(nmk), 1e-6f));
            const float bt  = betaT[tt];
            const float c1  = bt * kproj;
            const float c2  = bt * vv;

            float ktlj[SC], qj[SC];
            #pragma unroll
            for (int dd = 0; dd < SC; ++dd){
                ktlj[dd] = rlane(ktl, jbase + dd);
                qj[dd]   = rlane(qv,  jbase + dd);
            }

            // phase B: S -= b*ktld(x)kproj ; S += b*kn(x)v ; o partial = S^T q
            float o0 = 0.f, o1 = 0.f;
            #pragma unroll
            for (int dd = 0; dd < SC; dd += 2){
                float s0 = fmaf(-ktlj[dd], c1, s[dd]);
                s0 = fmaf(knj[dd], c2, s0);
                s[dd] = s0; o0 = fmaf(s0, qj[dd], o0);
                float s1 = fmaf(-ktlj[dd + 1], c1, s[dd + 1]);
                s1 = fmaf(knj[dd + 1], c2, s1);
                s[dd + 1] = s1; o1 = fmaf(s1, qj[dd + 1], o1);
            }
            oTw[w][tt * 64 + l] = o0 + o1;   // wave-private, no sync needed
        }
        __syncthreads();   // T2: all oTw complete

        // reduce o across waves + store (wave w handles steps 4w..4w+3)
        #pragma unroll
        for (int rr = 0; rr < 4; ++rr){
            const int tt2 = (w << 2) + rr;
            const float o = oTw[0][tt2 * 64 + l] + oTw[1][tt2 * 64 + l]
                          + oTw[2][tt2 * 64 + l] + oTw[3][tt2 * 64 + l];
            O[cbase + (size_t)(t0 + tt2) * 1024 + l] = (f16)o;
        }
    }
}

// ---------------- workspace layout (bytes), total ~107 MB ----------------
#define OFF_XN    ((size_t)0)                     // 16384*1024 f16 = 32 MB  (later: O)
#define OFF_WCAT  ((size_t)33554432)              // 4*1024*1024 f16 = 8 MB
#define OFF_WOT   ((size_t)41943040)              // 1024*1024 f16  =  2 MB
#define OFF_BETA  ((size_t)44040192)              // 128*2048 f32   =  1 MB
#define OFF_V     ((size_t)45088768)              // 16384*1024 f16 = 32 MB
#define OFF_A     ((size_t)78643200)              // 16384*1024 f16 = 32 MB
#define WS_NEED   ((size_t)112197632)

extern "C" void kernel_launch(void* const* d_in, const int* in_sizes, int n_in,
                              void* d_out, int out_size, void* d_ws, size_t ws_size,
                              hipStream_t stream)
{
    const float* x   = (const float*)d_in[0];
    const float* lng = (const float*)d_in[1];
    const float* lnb = (const float*)d_in[2];
    const float* Wq  = (const float*)d_in[3];
    const float* Wk  = (const float*)d_in[4];
    const float* Wv  = (const float*)d_in[5];
    const float* Wa  = (const float*)d_in[6];
    const float* ba  = (const float*)d_in[7];
    const float* Wb  = (const float*)d_in[8];
    const float* bb  = (const float*)d_in[9];
    const float* rgm = (const float*)d_in[10];
    const float* Wo  = (const float*)d_in[11];
    float* out = (float*)d_out;

    if (ws_size < WS_NEED){
        sentinel_fill<<<(out_size + 255) / 256, 256, 0, stream>>>(out, out_size);
        return;
    }

    char* ws = (char*)d_ws;
    f16*   xn   = (f16*)(ws + OFF_XN);
    f16*   wcat = (f16*)(ws + OFF_WCAT);
    f16*   wot  = (f16*)(ws + OFF_WOT);
    float* betw = (float*)(ws + OFF_BETA);
    f16*   Vbuf = (f16*)(ws + OFF_V);
    f16*   Abuf = (f16*)(ws + OFF_A);
    f16*   Qbuf = (f16*)d_out;                    // 32 MB
    f16*   Kbuf = Qbuf + (size_t)16384 * 1024;    // 32 MB (d_out total = 64 MB)
    f16*   Obuf = xn;                             // reuse xn slot after it's dead

    ln_kernel<<<16384, 256, 0, stream>>>(x, lng, lnb, xn);
    transpose5<<<dim3(32, 32, 5), dim3(32, 8), 0, stream>>>(Wq, Wk, Wv, Wa, Wo, wcat, wot);
    gemm_bt<0><<<dim3(128, 32), 256, 0, stream>>>(xn, wcat, 16384, 4096, 1024,
                                                  ba, nullptr, nullptr, Qbuf, Kbuf, Vbuf, Abuf);
    beta_kernel<<<16384, 256, 0, stream>>>(xn, Wb, bb, betw);
    scan_kernel<<<128, 256, 0, stream>>>(Qbuf, Kbuf, Vbuf, Abuf, betw, rgm, Obuf);
    gemm_bt<1><<<dim3(128, 8), 256, 0, stream>>>(Obuf, wot, 16384, 1024, 1024,
                                                 nullptr, x, out, nullptr, nullptr, nullptr, nullptr);
}

// Round 5
// 2346.831 us; speedup vs baseline: 3.2164x; 1.1021x over previous
//
#include <hip/hip_runtime.h>

typedef unsigned short u16;
typedef unsigned int   u32;
typedef _Float16       f16;
typedef __attribute__((ext_vector_type(4))) _Float16 v4h;
typedef __attribute__((ext_vector_type(8))) _Float16 v8h;   // MFMA A/B frag (4 VGPRs)
typedef __attribute__((ext_vector_type(4))) float    v4f;   // MFMA C/D frag

#define TT 2048
#define BB 8

static __device__ __forceinline__ float sigmoidf_(float x){
    return 1.0f / (1.0f + __expf(-x));
}
static __device__ __forceinline__ float allreduce64(float v){
    #pragma unroll
    for (int off = 32; off > 0; off >>= 1) v += __shfl_xor(v, off, 64);
    return v;
}

// Wave64 sum via DPP (VALU-only). row_shr 1/2/4/8 + row_bcast 15/31; lane 63 total.
static __device__ __forceinline__ float wave_sum64(float x){
    int t;
    t = __builtin_amdgcn_update_dpp(0, __float_as_int(x), 0x111, 0xf, 0xf, true); x += __int_as_float(t);
    t = __builtin_amdgcn_update_dpp(0, __float_as_int(x), 0x112, 0xf, 0xf, true); x += __int_as_float(t);
    t = __builtin_amdgcn_update_dpp(0, __float_as_int(x), 0x114, 0xf, 0xf, true); x += __int_as_float(t);
    t = __builtin_amdgcn_update_dpp(0, __float_as_int(x), 0x118, 0xf, 0xf, true); x += __int_as_float(t);
    t = __builtin_amdgcn_update_dpp(0, __float_as_int(x), 0x142, 0xf, 0xf, true); x += __int_as_float(t);
    t = __builtin_amdgcn_update_dpp(0, __float_as_int(x), 0x143, 0xf, 0xf, true); x += __int_as_float(t);
    return __int_as_float(__builtin_amdgcn_readlane(__float_as_int(x), 63));
}
static __device__ __forceinline__ float rlane(float v, int lane){
    return __int_as_float(__builtin_amdgcn_readlane(__float_as_int(v), lane));
}

// ---------------- diagnostic: fills d_out with sentinel if ws too small ----------------
__global__ __launch_bounds__(256) void sentinel_fill(float* __restrict__ out, int n){
    int i = blockIdx.x * 256 + threadIdx.x;
    if (i < n) out[i] = 12345.0f;
}

// ---------------- LayerNorm: x (16384x1024 f32) -> xn (fp16) ----------------
__global__ __launch_bounds__(256) void ln_kernel(
    const float* __restrict__ x, const float* __restrict__ g,
    const float* __restrict__ bta, f16* __restrict__ xn)
{
    const int row = blockIdx.x;
    const int tid = threadIdx.x;
    const float4 v = ((const float4*)(x + (size_t)row * 1024))[tid];
    float s  = v.x + v.y + v.z + v.w;
    float s2 = v.x*v.x + v.y*v.y + v.z*v.z + v.w*v.w;
    #pragma unroll
    for (int off = 32; off > 0; off >>= 1){
        s  += __shfl_xor(s,  off, 64);
        s2 += __shfl_xor(s2, off, 64);
    }
    __shared__ float rs[4], rq[4];
    const int wv = tid >> 6, lane = tid & 63;
    if (lane == 0){ rs[wv] = s; rq[wv] = s2; }
    __syncthreads();
    s  = rs[0] + rs[1] + rs[2] + rs[3];
    s2 = rq[0] + rq[1] + rq[2] + rq[3];
    const float mu   = s * (1.0f / 1024.0f);
    const float var  = s2 * (1.0f / 1024.0f) - mu * mu;
    const float rstd = rsqrtf(var + 1e-5f);
    const float4 gv = ((const float4*)g)[tid];
    const float4 bv = ((const float4*)bta)[tid];
    v4h o;
    o.x = (f16)((v.x - mu) * rstd * gv.x + bv.x);
    o.y = (f16)((v.y - mu) * rstd * gv.y + bv.y);
    o.z = (f16)((v.z - mu) * rstd * gv.z + bv.z);
    o.w = (f16)((v.w - mu) * rstd * gv.w + bv.w);
    ((v4h*)(xn + (size_t)row * 1024))[tid] = o;
}

// ------- transpose+cast 5 weight mats (1024x1024 f32, [k][n]) -> fp16 [n][k] -------
__global__ __launch_bounds__(256) void transpose5(
    const float* __restrict__ Wq, const float* __restrict__ Wk,
    const float* __restrict__ Wv, const float* __restrict__ Wa,
    const float* __restrict__ Wo, f16* __restrict__ wcat, f16* __restrict__ wot)
{
    __shared__ float tile[32][33];
    const int z = blockIdx.z;
    const float* src = (z==0)?Wq:(z==1)?Wk:(z==2)?Wv:(z==3)?Wa:Wo;
    f16* dst = (z < 4) ? (wcat + (size_t)z * 1024 * 1024) : wot;
    const int bx = blockIdx.x * 32, by = blockIdx.y * 32;
    const int tx = threadIdx.x, ty = threadIdx.y;
    #pragma unroll
    for (int i = 0; i < 4; ++i)
        tile[ty + i*8][tx] = src[(size_t)(by + ty + i*8) * 1024 + bx + tx];
    __syncthreads();
    #pragma unroll
    for (int i = 0; i < 4; ++i)
        dst[(size_t)(bx + ty + i*8) * 1024 + by + tx] = (f16)tile[tx][ty + i*8];
}

// ---------------- fp16 MFMA GEMM, B transposed (N x K). BM=BN=128, BK=64 ----------------
template<int MODE>
__global__ __launch_bounds__(256) void gemm_bt(
    const f16* __restrict__ A, const f16* __restrict__ Bt,
    int M, int N, int K,
    const float* __restrict__ ba, const float* __restrict__ resid,
    float* __restrict__ Cf,
    f16* __restrict__ Qb, f16* __restrict__ Kb,
    f16* __restrict__ Vb, f16* __restrict__ Ab)
{
    __shared__ f16 As[128 * 72];
    __shared__ f16 Bs[128 * 72];
    const int tid = threadIdx.x;
    const int bm = blockIdx.x, bn = blockIdx.y;
    const int wv = tid >> 6, lane = tid & 63;
    const int l15 = lane & 15, quad = lane >> 4;
    const int mb = (wv >> 1) * 64, nb = (wv & 1) * 64;
    v4f acc[4][4];
    const v4f vzero = {0.0f, 0.0f, 0.0f, 0.0f};
    #pragma unroll
    for (int i = 0; i < 4; ++i)
        #pragma unroll
        for (int j = 0; j < 4; ++j) acc[i][j] = vzero;

    const f16* Ag = A  + (size_t)bm * 128 * K;
    const f16* Bg = Bt + (size_t)bn * 128 * K;

    for (int k0 = 0; k0 < K; k0 += 64){
        __syncthreads();
        #pragma unroll
        for (int it = 0; it < 4; ++it){
            const int ch = tid + it * 256;
            const int r = ch >> 3, c = ch & 7;
            const uint4 da = *(const uint4*)(Ag + (size_t)r * K + k0 + c * 8);
            *(uint4*)(&As[r * 72 + c * 8]) = da;
            const uint4 db = *(const uint4*)(Bg + (size_t)r * K + k0 + c * 8);
            *(uint4*)(&Bs[r * 72 + c * 8]) = db;
        }
        __syncthreads();
        #pragma unroll
        for (int kk = 0; kk < 2; ++kk){
            v8h af[4], bfr[4];
            #pragma unroll
            for (int i = 0; i < 4; ++i){
                af[i]  = *(const v8h*)(&As[(mb + i*16 + l15) * 72 + kk*32 + quad*8]);
                bfr[i] = *(const v8h*)(&Bs[(nb + i*16 + l15) * 72 + kk*32 + quad*8]);
            }
            #pragma unroll
            for (int i = 0; i < 4; ++i)
                #pragma unroll
                for (int j = 0; j < 4; ++j)
                    acc[i][j] = __builtin_amdgcn_mfma_f32_16x16x32_f16(af[i], bfr[j], acc[i][j], 0, 0, 0);
        }
    }
    const int seg = (bn * 128) >> 10;
    f16* dst = (seg == 0) ? Qb : (seg == 1) ? Kb : (seg == 2) ? Vb : Ab;
    #pragma unroll
    for (int i = 0; i < 4; ++i){
        #pragma unroll
        for (int j = 0; j < 4; ++j){
            const int col = bn * 128 + nb + j * 16 + l15;
            const int c   = col & 1023;
            #pragma unroll
            for (int r = 0; r < 4; ++r){
                const int row = bm * 128 + mb + i * 16 + quad * 4 + r;
                float val = acc[i][j][r];
                if (MODE == 0){
                    if (seg == 3) val = sigmoidf_(val + ba[c]);
                    dst[(size_t)row * 1024 + c] = (f16)val;
                } else {
                    Cf[(size_t)row * N + col] = val + resid[(size_t)row * N + col];
                }
            }
        }
    }
}

// ---------------- beta: sigmoid(xn @ Wb + bb), stored chain-major [b*16+h][t] ----------------
__global__ __launch_bounds__(256) void beta_kernel(
    const f16* __restrict__ xn, const float* __restrict__ Wb,
    const float* __restrict__ bb, float* __restrict__ betaw)
{
    const int row = blockIdx.x;
    const int b = row >> 11, t = row & 2047;
    const int wv = threadIdx.x >> 6, lane = threadIdx.x & 63;
    const f16* xr = xn + (size_t)row * 1024;
    #pragma unroll
    for (int hh = 0; hh < 4; ++hh){
        const int h = wv * 4 + hh;
        float acc = 0.0f;
        #pragma unroll 4
        for (int k = lane; k < 1024; k += 64)
            acc += (float)xr[k] * Wb[k * 16 + h];
        acc = allreduce64(acc);
        if (lane == 0)
            betaw[((size_t)(b * 16 + h)) * 2048 + t] = sigmoidf_(acc + bb[h]);
    }
}

// ---------------- sequential scan v4: M/k_tilde hoisted to a tile preamble ----------------
// M_t, Mk_t, ktl_t depend only on k and gm (never on S). Per 16-step tile:
//   P1: 16 k-norms (4 indep DPP chains per wave, pipelined) -> rnkT
//   P2: bulk m[dd] recurrence (1-FMA-deep, fully pipelined) -> mk partials in sOT
//   P3: one cross-wave reduce + DPP norm for all 16 ktl vectors -> ktlT
// The per-step serial loop is then ONLY the S recurrence with a single b32
// kproj exchange barrier. ktl/q readlanes issue before the barrier.
#define SC 16
__global__ __launch_bounds__(256, 1) void scan_kernel(
    const f16* __restrict__ Qb, const f16* __restrict__ Kb,
    const f16* __restrict__ Vb, const f16* __restrict__ Ab,
    const float* __restrict__ beta, const float* __restrict__ rgm,
    f16* __restrict__ O)
{
    const int chain = blockIdx.x;           // b*16 + h
    const int b = chain >> 4, h = chain & 15;
    const int tid = threadIdx.x;
    const int w = __builtin_amdgcn_readfirstlane(tid) >> 6;   // wave-uniform
    const int l = tid & 63;
    const int jbase = w << 4;
    const float gm = sigmoidf_(rgm[h]);

    __shared__ f16 tQ[SC * 64], tK[SC * 64], tV[SC * 64], tA[SC * 64];
    __shared__ float betaT[SC];
    __shared__ float rnkT[SC];                 // 1/max(||k_t||,1e-12)
    __shared__ float ktlT[SC * 64];            // k_tilde, f32
    __shared__ float sOT[4096];                // preamble: mk partials [t][wv][l]; S-loop: oTw [w][t][l]
    __shared__ float redA[2][256];             // kproj partials, dbuf on t&1

    float m[SC], s[SC];
    #pragma unroll
    for (int dd = 0; dd < SC; ++dd){
        m[dd] = (jbase + dd == l) ? 1e-6f : 0.0f;  // M0 = EPS*I
        s[dd] = 0.0f;
    }

    const size_t cbase = ((size_t)(b * TT)) * 1024 + h * 64;
    const int r = tid >> 2, j4 = tid & 3;          // staging: row r (tensor,step), 32B chunk j4
    const int tens = r >> 4, str = r & 15;
    const f16* sg = (tens == 0) ? Qb : (tens == 1) ? Kb : (tens == 2) ? Vb : Ab;
    f16* sl = (tens == 0) ? tQ : (tens == 1) ? tK : (tens == 2) ? tV : tA;

    for (int t0 = 0; t0 < TT; t0 += SC){
        // ---- stage 16 steps of q/k/v/a (+beta) into LDS ----
        {
            const uint4* gp = (const uint4*)(sg + cbase + (size_t)(t0 + str) * 1024 + j4 * 16);
            const uint4 d0 = gp[0], d1 = gp[1];
            *(uint4*)(sl + str * 64 + j4 * 16)     = d0;
            *(uint4*)(sl + str * 64 + j4 * 16 + 8) = d1;
            if (tid < SC) betaT[tid] = beta[(size_t)chain * TT + t0 + tid];
        }
        __syncthreads();   // T1: tiles ready

        // ---- P1: k-norms for this wave's 4 steps (independent DPP chains) ----
        {
            float kv4[4];
            #pragma unroll
            for (int rr = 0; rr < 4; ++rr)
                kv4[rr] = (float)tK[((w << 2) + rr) * 64 + l];
            #pragma unroll
            for (int rr = 0; rr < 4; ++rr){
                const float nk = wave_sum64(kv4[rr] * kv4[rr]);
                if (l == 0)
                    rnkT[(w << 2) + rr] = __builtin_amdgcn_rcpf(fmaxf(sqrtf(nk), 1e-12f));
            }
        }
        __syncthreads();   // P1 done

        // ---- P2: bulk M recurrence + mk partials for all 16 steps ----
        #pragma unroll
        for (int t = 0; t < SC; ++t){
            const float knl = (float)tK[t * 64 + l] * rnkT[t];
            float knj2[SC];
            #pragma unroll
            for (int dd = 0; dd < SC; ++dd) knj2[dd] = rlane(knl, jbase + dd);
            float mk0 = 0.f, mk1 = 0.f;
            #pragma unroll
            for (int dd = 0; dd < SC; dd += 2){
                m[dd]     = fmaf(gm, m[dd],     knl * knj2[dd]);
                mk0 = fmaf(m[dd], knj2[dd], mk0);
                m[dd + 1] = fmaf(gm, m[dd + 1], knl * knj2[dd + 1]);
                mk1 = fmaf(m[dd + 1], knj2[dd + 1], mk1);
            }
            sOT[(t << 8) + (w << 6) + l] = mk0 + mk1;
        }
        __syncthreads();   // P2 done

        // ---- P3: reduce mk + normalize ktl for this wave's 4 steps ----
        {
            #pragma unroll
            for (int rr = 0; rr < 4; ++rr){
                const int t = (w << 2) + rr;
                const float mkf = sOT[(t << 8) + l] + sOT[(t << 8) + 64 + l]
                                + sOT[(t << 8) + 128 + l] + sOT[(t << 8) + 192 + l];
                const float nmk = wave_sum64(mkf * mkf);
                ktlT[t * 64 + l] = mkf * __builtin_amdgcn_rcpf(fmaxf(sqrtf(nmk), 1e-6f));
            }
        }
        __syncthreads();   // P3 done: ktlT ready; sOT free for oTw reuse

        // ---- serial S loop: one b32 barrier per step ----
        #pragma unroll 2
        for (int tt = 0; tt < SC; ++tt){
            const float knl  = (float)tK[tt * 64 + l] * rnkT[tt];
            const float avl  = (float)tA[tt * 64 + l];
            const float qvl  = (float)tQ[tt * 64 + l];
            const float vvl  = (float)tV[tt * 64 + l];
            const float ktll = ktlT[tt * 64 + l];
            const float bt   = betaT[tt];

            float knj[SC], aj[SC];
            #pragma unroll
            for (int dd = 0; dd < SC; ++dd){
                knj[dd] = rlane(knl, jbase + dd);
                aj[dd]  = rlane(avl, jbase + dd);
            }

            // phase A: S row-scale + kproj partial
            float kp0 = 0.f, kp1 = 0.f;
            #pragma unroll
            for (int dd = 0; dd < SC; dd += 2){
                s[dd]     *= aj[dd];
                kp0 = fmaf(knj[dd], s[dd], kp0);
                s[dd + 1] *= aj[dd + 1];
                kp1 = fmaf(knj[dd + 1], s[dd + 1], kp1);
            }
            redA[tt & 1][(w << 6) + l] = kp0 + kp1;

            // pre-barrier readlanes (independent of kproj)
            float ktlj[SC], qj[SC];
            #pragma unroll
            for (int dd = 0; dd < SC; ++dd){
                ktlj[dd] = rlane(ktll, jbase + dd);
                qj[dd]   = rlane(qvl,  jbase + dd);
            }
            __syncthreads();                               // the one per-step barrier

            const float kproj = redA[tt & 1][l] + redA[tt & 1][64 + l]
                              + redA[tt & 1][128 + l] + redA[tt & 1][192 + l];
            const float c1 = bt * kproj;
            const float c2 = bt * vvl;

            // phase B: S -= b*ktld(x)kproj ; S += b*kn(x)v ; o partial = S^T q
            float o0 = 0.f, o1 = 0.f;
            #pragma unroll
            for (int dd = 0; dd < SC; dd += 2){
                float s0 = fmaf(-ktlj[dd], c1, s[dd]);
                s0 = fmaf(knj[dd], c2, s0);
                s[dd] = s0; o0 = fmaf(s0, qj[dd], o0);
                float s1 = fmaf(-ktlj[dd + 1], c1, s[dd + 1]);
                s1 = fmaf(knj[dd + 1], c2, s1);
                s[dd + 1] = s1; o1 = fmaf(s1, qj[dd + 1], o1);
            }
            sOT[(w << 10) + (tt << 6) + l] = o0 + o1;      // oTw, wave-private
        }
        __syncthreads();   // T2: all o partials complete

        // reduce o across waves + store (wave w handles steps 4w..4w+3)
        #pragma unroll
        for (int rr = 0; rr < 4; ++rr){
            const int tt2 = (w << 2) + rr;
            const float o = sOT[(tt2 << 6) + l] + sOT[1024 + (tt2 << 6) + l]
                          + sOT[2048 + (tt2 << 6) + l] + sOT[3072 + (tt2 << 6) + l];
            O[cbase + (size_t)(t0 + tt2) * 1024 + l] = (f16)o;
        }
    }
}

// ---------------- workspace layout (bytes), total ~107 MB ----------------
#define OFF_XN    ((size_t)0)                     // 16384*1024 f16 = 32 MB  (later: O)
#define OFF_WCAT  ((size_t)33554432)              // 4*1024*1024 f16 = 8 MB
#define OFF_WOT   ((size_t)41943040)              // 1024*1024 f16  =  2 MB
#define OFF_BETA  ((size_t)44040192)              // 128*2048 f32   =  1 MB
#define OFF_V     ((size_t)45088768)              // 16384*1024 f16 = 32 MB
#define OFF_A     ((size_t)78643200)              // 16384*1024 f16 = 32 MB
#define WS_NEED   ((size_t)112197632)

extern "C" void kernel_launch(void* const* d_in, const int* in_sizes, int n_in,
                              void* d_out, int out_size, void* d_ws, size_t ws_size,
                              hipStream_t stream)
{
    const float* x   = (const float*)d_in[0];
    const float* lng = (const float*)d_in[1];
    const float* lnb = (const float*)d_in[2];
    const float* Wq  = (const float*)d_in[3];
    const float* Wk  = (const float*)d_in[4];
    const float* Wv  = (const float*)d_in[5];
    const float* Wa  = (const float*)d_in[6];
    const float* ba  = (const float*)d_in[7];
    const float* Wb  = (const float*)d_in[8];
    const float* bb  = (const float*)d_in[9];
    const float* rgm = (const float*)d_in[10];
    const float* Wo  = (const float*)d_in[11];
    float* out = (float*)d_out;

    if (ws_size < WS_NEED){
        sentinel_fill<<<(out_size + 255) / 256, 256, 0, stream>>>(out, out_size);
        return;
    }

    char* ws = (char*)d_ws;
    f16*   xn   = (f16*)(ws + OFF_XN);
    f16*   wcat = (f16*)(ws + OFF_WCAT);
    f16*   wot  = (f16*)(ws + OFF_WOT);
    float* betw = (float*)(ws + OFF_BETA);
    f16*   Vbuf = (f16*)(ws + OFF_V);
    f16*   Abuf = (f16*)(ws + OFF_A);
    f16*   Qbuf = (f16*)d_out;                    // 32 MB
    f16*   Kbuf = Qbuf + (size_t)16384 * 1024;    // 32 MB (d_out total = 64 MB)
    f16*   Obuf = xn;                             // reuse xn slot after it's dead

    ln_kernel<<<16384, 256, 0, stream>>>(x, lng, lnb, xn);
    transpose5<<<dim3(32, 32, 5), dim3(32, 8), 0, stream>>>(Wq, Wk, Wv, Wa, Wo, wcat, wot);
    gemm_bt<0><<<dim3(128, 32), 256, 0, stream>>>(xn, wcat, 16384, 4096, 1024,
                                                  ba, nullptr, nullptr, Qbuf, Kbuf, Vbuf, Abuf);
    beta_kernel<<<16384, 256, 0, stream>>>(xn, Wb, bb, betw);
    scan_kernel<<<128, 256, 0, stream>>>(Qbuf, Kbuf, Vbuf, Abuf, betw, rgm, Obuf);
    gemm_bt<1><<<dim3(128, 8), 256, 0, stream>>>(Obuf, wot, 16384, 1024, 1024,
                                                 nullptr, x, out, nullptr, nullptr, nullptr, nullptr);
}